// Round 17
// baseline (2545.925 us; speedup 1.0000x reference)
//
#include <hip/hip_runtime.h>

#define DT_C 0.1f
#define LOG2E 1.4426950408889634f
#define S_ACC 1920   // acc weight 0.9^(2047-t): t<1920 contributes <1.4e-6

typedef _Float16 h2 __attribute__((ext_vector_type(2)));

__device__ __forceinline__ float sigx(float z) {
    return __builtin_amdgcn_rcpf(1.0f + __builtin_amdgcn_exp2f(-LOG2E * z));
}
__device__ __forceinline__ float fdot2(h2 a, h2 b, float c) {
    return __builtin_amdgcn_fdot2(a, b, c, false);
}
__device__ __forceinline__ unsigned pkh(float lo, float hi) {
    h2 v = {(_Float16)lo, (_Float16)hi};   // RNE casts
    return __builtin_bit_cast(unsigned, v);
}

// B=256, S=2048, I=1, H=128, O=1.
// R17: ONE WAVE PER ROW — barrier-free recurrence. 256 blocks x 64 threads.
// A single wave is implicitly synchronized: the h/hatt exchange through LDS
// needs NO __syncthreads (in-order DS pipe, write->read within one wave).
// Lane l owns rows jA=l, jB=l+64 with FULL-k dots: 64 dot2/row/matvec, no
// cross-lane reduction, no roles, no red4/dppswap. Exchange = 1 packed
// ds_write_b32 {h[l],h[l+64]} + 16 broadcast ds_read_b128 per tick.
// 256 dot2/step = the instruction minimum (32768 MAC / 128 MAC-per-dot2).
// W_rec/W_att in VGPRs (256 regs, waves_per_eu(1,1) budget 512); W_acc in
// LDS, used only for the last 128 steps (S_ACC, error < 1.4e-6).
// fp32 state + folded-bias exp2/rcp nonlins (R13-verified numerics).
__global__ __attribute__((amdgpu_waves_per_eu(1, 1))) __launch_bounds__(64)
void clnm_kernel(const float* __restrict__ x,      // [256,2048]
                 const float* __restrict__ W_in,   // [128,1]
                 const float* __restrict__ b_in,   // [128]
                 const float* __restrict__ W_rec,  // [128,128]
                 const float* __restrict__ b_rec,  // [128]
                 const float* __restrict__ tau,    // [128]
                 const float* __restrict__ W_att,  // [128,128]
                 const float* __restrict__ b_att,  // [128]
                 const float* __restrict__ W_ev,   // [1,2]
                 const float* __restrict__ b_ev,   // [1]
                 const float* __restrict__ W_acc,  // [128,128]
                 const float* __restrict__ b_acc,  // [128]
                 const float* __restrict__ W_out,  // [1,128]
                 const float* __restrict__ b_out,  // [1]
                 float* __restrict__ out,          // [256]
                 float* __restrict__ out_ew)       // [256,2048]
{
    const int l = threadIdx.x;    // 0..63
    const int r = blockIdx.x;

    __shared__ __align__(16) float    x_stage[2048];        // 8 KB
    __shared__ __align__(16) float4   xe_lds[2048];         // 32 KB
    __shared__ __align__(16) unsigned h_l[64];              // packed {h[l], h[l+64]}
    __shared__ __align__(16) unsigned ha_l[64];
    __shared__ __align__(16) unsigned wacc_l[2][64][68];    // paired {k,k+64}, 16B-aligned rows

    const float wev0 = W_ev[0], wev1 = W_ev[1], bev = b_ev[0], bout = b_out[0];

    // ---- stage x ----
    const float4* xg4 = (const float4*)(x + (size_t)r * 2048);
#pragma unroll
    for (int i = 0; i < 8; ++i) ((float4*)x_stage)[l + 64 * i] = xg4[l + 64 * i];
    h_l[l] = 0u; ha_l[l] = 0u;
    __syncthreads();

    // ---- per-step scalars: 32 steps/lane ----
    {
        const int s0 = l * 32;
        float prev = (l == 0) ? 0.0f : x_stage[s0 - 1];
        for (int i = 0; i < 32; ++i) {
            const int s = s0 + i;
            const float xv = x_stage[s];
            const float e = (s == 0) ? 0.0f : sigx(fmaf(wev0, xv, fmaf(wev1, prev, bev)));
            prev = xv;
            const float xn = (s < 2047) ? x_stage[s + 1] : 0.0f;
            xe_lds[s] = make_float4(xn, DT_C * (1.0f + e), 0.1f * e, e);
        }
    }

    // ---- weights: W_rec/W_att -> VGPRs paired {k, k+64}; W_acc -> LDS ----
    h2 wR[2][64], wA[2][64];
#pragma unroll
    for (int g = 0; g < 2; ++g) {
        const float* pr = W_rec + (size_t)(l + 64 * g) * 128;
        const float* pa = W_att + (size_t)(l + 64 * g) * 128;
        const float* pc = W_acc + (size_t)(l + 64 * g) * 128;
#pragma unroll
        for (int i = 0; i < 64; ++i) {
            wR[g][i] = h2{(_Float16)pr[i], (_Float16)pr[i + 64]};
            wA[g][i] = h2{(_Float16)pa[i], (_Float16)pa[i + 64]};
            wacc_l[g][l][i] = pkh(pc[i], pc[i + 64]);
        }
    }

    // ---- per-lane constants for rows jA=l, jB=l+64 (folded exp2 args) ----
    const float m2 = -2.0f * LOG2E;
    float bR2m[2], m2win[2], m2bin[2], bA1m[2], bC2m[2], ti[2], wo[2];
#pragma unroll
    for (int g = 0; g < 2; ++g) {
        const int j = l + 64 * g;
        bR2m[g]  = m2 * b_rec[j];
        m2win[g] = m2 * W_in[j];
        m2bin[g] = m2 * b_in[j];
        bA1m[g]  = -LOG2E * b_att[j];
        bC2m[g]  = m2 * b_acc[j];
        ti[g]    = 1.0f / fminf(fmaxf(tau[j], 0.1f), 10.0f);
        wo[g]    = W_out[j];
    }

    __syncthreads();   // xe_lds visible to all lanes (the ONLY in-loop-relevant barrier)

    // ---- out_ew coalesced from xe_lds.w ----
    {
        float* ewg = out_ew + (size_t)r * 2048;
#pragma unroll
        for (int i = 0; i < 8; ++i) {
            const int m = l + 64 * i;
            ((float4*)ewg)[m] = make_float4(xe_lds[4 * m].w, xe_lds[4 * m + 1].w,
                                            xe_lds[4 * m + 2].w, xe_lds[4 * m + 3].w);
        }
    }

    float hv[2] = {0.f, 0.f}, ac[2] = {0.f, 0.f};
    float kkti[2], hpre[2];
#pragma unroll
    for (int g = 0; g < 2; ++g) {
        const float ic0 = fmaf(2.0f, __builtin_amdgcn_rcpf(
            1.0f + __builtin_amdgcn_exp2f(fmaf(m2win[g], x_stage[0], m2bin[g]))), -1.0f);
        kkti[g] = DT_C * ti[g];        // ew_0 = 0
        hpre[g] = kkti[g] * ic0;       // h_0 = 0
    }

    const uint4* hap = (const uint4*)ha_l;
    const uint4* hp  = (const uint4*)h_l;

    for (int s = 0; s < 2048; ++s) {
        const float4 xe = xe_lds[s];   // {x_{s+1}, kk_s, 0.1*ew_s, ew_s}

        // ---- tick1: REC on hatt(s) — 16 broadcast b128 reads + 128 dot2 ----
        uint4 q[16];
#pragma unroll
        for (int i = 0; i < 16; ++i) q[i] = hap[i];
        float c0[4] = {0,0,0,0}, c1[4] = {0,0,0,0};
#pragma unroll
        for (int i = 0; i < 16; ++i) {
            const h2 a0 = __builtin_bit_cast(h2, q[i].x);
            const h2 a1 = __builtin_bit_cast(h2, q[i].y);
            const h2 a2 = __builtin_bit_cast(h2, q[i].z);
            const h2 a3 = __builtin_bit_cast(h2, q[i].w);
            c0[0] = fdot2(wR[0][4*i+0], a0, c0[0]);
            c0[1] = fdot2(wR[0][4*i+1], a1, c0[1]);
            c0[2] = fdot2(wR[0][4*i+2], a2, c0[2]);
            c0[3] = fdot2(wR[0][4*i+3], a3, c0[3]);
            c1[0] = fdot2(wR[1][4*i+0], a0, c1[0]);
            c1[1] = fdot2(wR[1][4*i+1], a1, c1[1]);
            c1[2] = fdot2(wR[1][4*i+2], a2, c1[2]);
            c1[3] = fdot2(wR[1][4*i+3], a3, c1[3]);
        }
        const float rs0 = (c0[0] + c0[1]) + (c0[2] + c0[3]);
        const float rs1 = (c1[0] + c1[1]) + (c1[2] + c1[3]);
        const float t0 = fmaf(2.0f, __builtin_amdgcn_rcpf(
            1.0f + __builtin_amdgcn_exp2f(fmaf(m2, rs0, bR2m[0]))), -1.0f);
        const float t1 = fmaf(2.0f, __builtin_amdgcn_rcpf(
            1.0f + __builtin_amdgcn_exp2f(fmaf(m2, rs1, bR2m[1]))), -1.0f);
        hv[0] = fmaf(kkti[0], t0, hpre[0]);
        hv[1] = fmaf(kkti[1], t1, hpre[1]);
        h_l[l] = pkh(hv[0], hv[1]);    // no barrier: wave-internal DS ordering

        // ---- tick2: ATT on h(s+1) ----
#pragma unroll
        for (int i = 0; i < 16; ++i) q[i] = hp[i];
        float d0[4] = {0,0,0,0}, d1[4] = {0,0,0,0};
#pragma unroll
        for (int i = 0; i < 16; ++i) {
            const h2 a0 = __builtin_bit_cast(h2, q[i].x);
            const h2 a1 = __builtin_bit_cast(h2, q[i].y);
            const h2 a2 = __builtin_bit_cast(h2, q[i].z);
            const h2 a3 = __builtin_bit_cast(h2, q[i].w);
            d0[0] = fdot2(wA[0][4*i+0], a0, d0[0]);
            d0[1] = fdot2(wA[0][4*i+1], a1, d0[1]);
            d0[2] = fdot2(wA[0][4*i+2], a2, d0[2]);
            d0[3] = fdot2(wA[0][4*i+3], a3, d0[3]);
            d1[0] = fdot2(wA[1][4*i+0], a0, d1[0]);
            d1[1] = fdot2(wA[1][4*i+1], a1, d1[1]);
            d1[2] = fdot2(wA[1][4*i+2], a2, d1[2]);
            d1[3] = fdot2(wA[1][4*i+3], a3, d1[3]);
        }
        const float as0 = (d0[0] + d0[1]) + (d0[2] + d0[3]);
        const float as1 = (d1[0] + d1[1]) + (d1[2] + d1[3]);
        const float att0 = __builtin_amdgcn_rcpf(
            1.0f + __builtin_amdgcn_exp2f(fmaf(-LOG2E, as0, bA1m[0])));
        const float att1 = __builtin_amdgcn_rcpf(
            1.0f + __builtin_amdgcn_exp2f(fmaf(-LOG2E, as1, bA1m[1])));
        ha_l[l] = pkh(hv[0] * att0, hv[1] * att1);

        // ---- late ACC (last 128 steps): weights from LDS ----
        if (s >= S_ACC) {
            const uint4* w0 = (const uint4*)&wacc_l[0][l][0];
            const uint4* w1 = (const uint4*)&wacc_l[1][l][0];
            float e0[4] = {0,0,0,0}, e1[4] = {0,0,0,0};
#pragma unroll
            for (int i = 0; i < 16; ++i) {
                const uint4 u0 = w0[i];
                const uint4 u1 = w1[i];
                e0[0] = fdot2(__builtin_bit_cast(h2, u0.x), __builtin_bit_cast(h2, q[i].x), e0[0]);
                e0[1] = fdot2(__builtin_bit_cast(h2, u0.y), __builtin_bit_cast(h2, q[i].y), e0[1]);
                e0[2] = fdot2(__builtin_bit_cast(h2, u0.z), __builtin_bit_cast(h2, q[i].z), e0[2]);
                e0[3] = fdot2(__builtin_bit_cast(h2, u0.w), __builtin_bit_cast(h2, q[i].w), e0[3]);
                e1[0] = fdot2(__builtin_bit_cast(h2, u1.x), __builtin_bit_cast(h2, q[i].x), e1[0]);
                e1[1] = fdot2(__builtin_bit_cast(h2, u1.y), __builtin_bit_cast(h2, q[i].y), e1[1]);
                e1[2] = fdot2(__builtin_bit_cast(h2, u1.z), __builtin_bit_cast(h2, q[i].z), e1[2]);
                e1[3] = fdot2(__builtin_bit_cast(h2, u1.w), __builtin_bit_cast(h2, q[i].w), e1[3]);
            }
            const float cs0 = (e0[0] + e0[1]) + (e0[2] + e0[3]);
            const float cs1 = (e1[0] + e1[1]) + (e1[2] + e1[3]);
            const float ct0 = fmaf(2.0f, __builtin_amdgcn_rcpf(
                1.0f + __builtin_amdgcn_exp2f(fmaf(m2, cs0, bC2m[0]))), -1.0f);
            const float ct1 = fmaf(2.0f, __builtin_amdgcn_rcpf(
                1.0f + __builtin_amdgcn_exp2f(fmaf(m2, cs1, bC2m[1]))), -1.0f);
            ac[0] = fmaf(xe.z, ct0, 0.9f * ac[0]);
            ac[1] = fmaf(xe.z, ct1, 0.9f * ac[1]);
        }

        // ---- off-chain: precompute kkti/hpre for step s+1 ----
        {
            const float4 xen = xe_lds[(s < 2047) ? s + 1 : 2047];
#pragma unroll
            for (int g = 0; g < 2; ++g) {
                const float icn = fmaf(2.0f, __builtin_amdgcn_rcpf(
                    1.0f + __builtin_amdgcn_exp2f(fmaf(m2win[g], xe.x, m2bin[g]))), -1.0f);
                const float kt = xen.y * ti[g];
                kkti[g] = kt;
                hpre[g] = fmaf(kt, icn, fmaf(-kt, hv[g], hv[g]));
            }
        }
    }

    // ---- Output: out[r] = sum_j (h_f + acc_f)[j] * W_out[j] + b_out ----
    float val = fmaf(hv[0] + ac[0], wo[0], (hv[1] + ac[1]) * wo[1]);
#pragma unroll
    for (int m = 1; m < 64; m <<= 1) val += __shfl_xor(val, m);
    if (l == 0) out[r] = val + bout;
}

extern "C" void kernel_launch(void* const* d_in, const int* in_sizes, int n_in,
                              void* d_out, int out_size, void* d_ws, size_t ws_size,
                              hipStream_t stream) {
    const float* x     = (const float*)d_in[0];
    const float* W_in  = (const float*)d_in[1];
    const float* b_in  = (const float*)d_in[2];
    const float* W_rec = (const float*)d_in[3];
    const float* b_rec = (const float*)d_in[4];
    const float* tau   = (const float*)d_in[5];
    const float* W_att = (const float*)d_in[6];
    const float* b_att = (const float*)d_in[7];
    const float* W_ev  = (const float*)d_in[8];
    const float* b_ev  = (const float*)d_in[9];
    const float* W_acc = (const float*)d_in[10];
    const float* b_acc = (const float*)d_in[11];
    const float* W_out = (const float*)d_in[12];
    const float* b_out = (const float*)d_in[13];

    float* out    = (float*)d_out;        // [256,1]
    float* out_ew = out + 256;            // [256,2048]

    clnm_kernel<<<256, 64, 0, stream>>>(x, W_in, b_in, W_rec, b_rec, tau,
                                        W_att, b_att, W_ev, b_ev,
                                        W_acc, b_acc, W_out, b_out,
                                        out, out_ew);
}